// Round 12
// baseline (410.696 us; speedup 1.0000x reference)
//
#include <hip/hip_runtime.h>
#include <math.h>

// CepstrumToImpulseResponse: per row r (131072 rows):
//   h[0] = exp(c[0]);  h[n] = (1/n) * sum_{k=1}^{min(n,255)} (k*c_k) * h[n-k]
//
// R12 = R11 with the far-part MAC engine switched from v_dot2_f32_f16
// (measured 1 MAC/lane/cyc) to v_pk_fma_f16 (hypothesis: full VOP rate =
// 2 MACs/lane/cyc -- CDNA's "2x fp16 vector rate"). Identical operand
// indexing (window pair x coefficient pair); accumulators become f16x2,
// split to f32 (a = f32(lo)+f32(hi)) before the unchanged f32 reduce+fixup.
// Precision: f16 accumulation adds ~1e-3 worst-case absolute error
// (threshold 2.09e-2; R11 floor was 2.4e-4 from f16 ring storage).
//
// Carried from R11: two-phase window (it<16: 128-wide, no coeff guards;
// it>=16: 256-wide), per-row 256-half f16 ring, lane-7 register forwarding
// of the newest 8 h's, 1-iter window prefetch, DPP 8-lane reduce, f32
// serial fixup k=1..7, register output staging, 256B/row coalesced flush.
// Launch bounds pinned at (256,4): (256,8) spilled twice (R6/R9).

constexpr int ROWS_PER_BLOCK = 32;   // 4 waves x 8 rows
constexpr int THREADS = 256;
constexpr int CLEN = 256;            // c row length (M+1)
constexpr int NOUT = 512;            // IR length
constexpr int RHALVES = 264;         // 256-half ring (512B) + 8 pad halves

typedef float f4 __attribute__((ext_vector_type(4)));
typedef _Float16 half2_t __attribute__((ext_vector_type(2)));

// B += WU * PP, packed f16 (2 MACs). Single VOP3P instruction.
#define PKFMA16(B, WU, PP) \
  asm("v_pk_fma_f16 %0, %1, %2, %0" : "+v"(B) : "v"(WU), "v"(PP))

// Sum v across each aligned 8-lane group; every lane gets the group total.
// quad_perm(1,0,3,2)=0xB1, quad_perm(2,3,0,1)=0x4E, row_half_mirror=0x141
__device__ __forceinline__ float row8_sum(float v) {
  int x;
  x = __builtin_amdgcn_update_dpp(0, __float_as_int(v), 0xB1, 0xF, 0xF, true);
  v += __int_as_float(x);
  x = __builtin_amdgcn_update_dpp(0, __float_as_int(v), 0x4E, 0xF, 0xF, true);
  v += __int_as_float(x);
  x = __builtin_amdgcn_update_dpp(0, __float_as_int(v), 0x141, 0xF, 0xF, true);
  v += __int_as_float(x);
  return v;
}

// One window pair (2 f16 in wu) against 8 outputs; output j uses P[ub+7-j].
#define DOTQ(P, wu, ub)                     \
      { PKFMA16(B0, (wu), P[(ub) + 7]);     \
        PKFMA16(B1, (wu), P[(ub) + 6]);     \
        PKFMA16(B2, (wu), P[(ub) + 5]);     \
        PKFMA16(B3, (wu), P[(ub) + 4]);     \
        PKFMA16(B4, (wu), P[(ub) + 3]);     \
        PKFMA16(B5, (wu), P[(ub) + 2]);     \
        PKFMA16(B6, (wu), P[(ub) + 1]);     \
        PKFMA16(B7, (wu), P[(ub) + 0]); }

// f16x2 accumulator split + reduce + fixup + ring write + staging/flush.
#define ITER_TAIL(Y0EXPR)                                                \
      const float a0 = row8_sum((float)B0.x + (float)B0.y);              \
      const float a1 = row8_sum((float)B1.x + (float)B1.y);              \
      const float a2 = row8_sum((float)B2.x + (float)B2.y);              \
      const float a3 = row8_sum((float)B3.x + (float)B3.y);              \
      const float a4 = row8_sum((float)B4.x + (float)B4.y);              \
      const float a5 = row8_sum((float)B5.x + (float)B5.y);              \
      const float a6 = row8_sum((float)B6.x + (float)B6.y);              \
      const float a7 = row8_sum((float)B7.x + (float)B7.y);              \
      const int n = it * 8;                                              \
      const f4 ivA = *(const f4*)(&INV[n]);                              \
      const f4 ivB = *(const f4*)(&INV[n + 4]);                          \
      const float y0 = (Y0EXPR);                                         \
      const float y1 = fmaf(kc1, y0, a1) * ivA.y;                        \
      const float y2 = fmaf(kc1, y1, fmaf(kc2, y0, a2)) * ivA.z;         \
      const float y3 = fmaf(kc1, y2, fmaf(kc2, y1,                       \
                          fmaf(kc3, y0, a3))) * ivA.w;                   \
      const float y4 = fmaf(kc1, y3, fmaf(kc2, y2, fmaf(kc3, y1,         \
                          fmaf(kc4, y0, a4)))) * ivB.x;                  \
      const float y5 = fmaf(kc1, y4, fmaf(kc2, y3, fmaf(kc3, y2,         \
                          fmaf(kc4, y1, fmaf(kc5, y0, a5))))) * ivB.y;   \
      const float y6 = fmaf(kc1, y5, fmaf(kc2, y4, fmaf(kc3, y3,         \
                          fmaf(kc4, y2, fmaf(kc5, y1,                    \
                          fmaf(kc6, y0, a6)))))) * ivB.z;                \
      const float y7 = fmaf(kc1, y6, fmaf(kc2, y5, fmaf(kc3, y4,         \
                          fmaf(kc4, y3, fmaf(kc5, y2, fmaf(kc6, y1,      \
                          fmaf(kc7, y0, a7)))))))  * ivB.w;              \
      uint4 wq;                                                          \
      wq.x = __builtin_bit_cast(uint, __builtin_amdgcn_cvt_pkrtz(y0, y1)); \
      wq.y = __builtin_bit_cast(uint, __builtin_amdgcn_cvt_pkrtz(y2, y3)); \
      wq.z = __builtin_bit_cast(uint, __builtin_amdgcn_cvt_pkrtz(y4, y5)); \
      wq.w = __builtin_bit_cast(uint, __builtin_amdgcn_cvt_pkrtz(y6, y7)); \
      qn = wq;                                                           \
      wo = (wo + 16) & 508;                                              \
      if (s == 0) {                                                      \
        *(uint4*)(Hb + wo) = wq;   /* same-wave DS ops are in-order */   \
      }                                                                  \
      if ((it & 7) == s) {                                               \
        ys0 = y0; ys1 = y1; ys2 = y2; ys3 = y3;                          \
        ys4 = y4; ys5 = y5; ys6 = y6; ys7 = y7;                          \
      }                                                                  \
      if ((it & 7) == 7) {                                               \
        f4 v0; v0.x = ys0; v0.y = ys1; v0.z = ys2; v0.w = ys3;           \
        f4 v1; v1.x = ys4; v1.y = ys5; v1.z = ys6; v1.w = ys7;           \
        *(f4*)(gp) = v0;                                                 \
        *(f4*)(gp + 4) = v1;                                             \
        gp += 64;                                                        \
      }

__global__ __launch_bounds__(THREADS, 4) void cep2ir_kernel(
    const float* __restrict__ c, float* __restrict__ out, int nrows) {
  __shared__ ushort HF[ROWS_PER_BLOCK][RHALVES];   // f16 h-history rings
  __shared__ float INV[NOUT];

  const int tid = threadIdx.x;
  const int lane = tid & 63;
  const int wid = tid >> 6;
  const int s = lane & 7;                  // sublane within 8-lane row group
  const int rl = (wid << 3) | (lane >> 3); // row within block, 0..31

  for (int i = tid; i < NOUT; i += THREADS)
    INV[i] = (i == 0) ? 0.0f : 1.0f / (float)i;
  // Zero all rings (as uints; RHALVES is even -> rows stay uint-aligned).
  uint* hz = (uint*)&HF[0][0];
  for (int i = tid; i < ROWS_PER_BLOCK * RHALVES / 2; i += THREADS)
    hz[i] = 0u;
  __syncthreads();  // uniform: all threads reach this before divergence

  const long long row = (long long)blockIdx.x * ROWS_PER_BLOCK + rl;
  if (row < nrows) {
    const float* __restrict__ crow = c + row * (long long)CLEN;

    const float kc1 = crow[1];
    const float kc2 = 2.0f * crow[2];
    const float kc3 = 3.0f * crow[3];
    const float kc4 = 4.0f * crow[4];
    const float kc5 = 5.0f * crow[5];
    const float kc6 = 6.0f * crow[6];
    const float kc7 = 7.0f * crow[7];
    const float h0val = expf(crow[0]);
    const bool is7 = (s == 7);

    char* __restrict__ Hb = (char*)&HF[rl][0];
    int wo = (-16) & 508;                    // ring write offset (bytes)
    float* __restrict__ gp = out + row * (long long)NOUT + 8 * s;

    uint4 qn; qn.x = 0u; qn.y = 0u; qn.z = 0u; qn.w = 0u;  // forwarded h's

    // Register output staging: lane s keeps the y's of the iteration with
    // (it&7)==s, then writes its own 32B slice at flush (coalesced).
    float ys0 = 0.f, ys1 = 0.f, ys2 = 0.f, ys3 = 0.f;
    float ys4 = 0.f, ys5 = 0.f, ys6 = 0.f, ys7 = 0.f;

    // ------------- Phase 1: it = 0..15, 128-wide window -------------
    // Lane s owns window pos p = 16s + eps, eps = 0..15 (p 0 = h[n-128],
    // p 127 = h[n-1]). Coef k = K1 + j - eps, K1 = 128 - 16s.
    // P1[u] = (kc(K1+7-u), kc(K1+6-u)), u = 0..21; window pair pp
    // (eps = 2pp, 2pp+1) for output j uses P1[2pp + 7 - j].
    // k range over all lanes: [2, 135] -> no clamping needed.
    // Ring byte of p: (16it + 256 + 32s + 2eps) mod 512. 32B lane stride.
    {
      const int K1 = 128 - 16 * s;
      half2_t P1[22];
#pragma unroll
      for (int u = 0; u < 22; ++u) {
        const int kx = K1 + 7 - u;          // in [2,135]
        P1[u] = __builtin_bit_cast(half2_t, __builtin_amdgcn_cvt_pkrtz(
                    (float)kx * crow[kx], (float)(kx - 1) * crow[kx - 1]));
      }

#pragma unroll 2
      for (int it = 0; it < 16; ++it) {
        const int b0 = (16 * it + 256 + 32 * s) & 508;
        const int b1 = (b0 + 16) & 508;
        const uint4 u0 = *(const uint4*)(Hb + b0);   // eps 0..7
        const uint4 u1r = *(const uint4*)(Hb + b1);  // eps 8..15
        // Newest 8 h's live at (s=7, eps 8..15): forward from registers.
        uint4 u1;
        u1.x = is7 ? qn.x : u1r.x;
        u1.y = is7 ? qn.y : u1r.y;
        u1.z = is7 ? qn.z : u1r.z;
        u1.w = is7 ? qn.w : u1r.w;

        half2_t B0 = {0, 0}, B1 = {0, 0}, B2 = {0, 0}, B3 = {0, 0};
        half2_t B4 = {0, 0}, B5 = {0, 0}, B6 = {0, 0}, B7 = {0, 0};
        DOTQ(P1, u0.x, 0)  DOTQ(P1, u0.y, 2)
        DOTQ(P1, u0.z, 4)  DOTQ(P1, u0.w, 6)
        DOTQ(P1, u1.x, 8)  DOTQ(P1, u1.y, 10)
        DOTQ(P1, u1.z, 12) DOTQ(P1, u1.w, 14)

        ITER_TAIL((it == 0) ? h0val : a0 * ivA.x)
      }
    }

    // ------------- Phase 2: it = 16..63, 256-wide window -------------
    // Lane s owns pos = 32s + eps, eps = 0..31. K = 256 - 32s.
    // P[u] = (kc(K+7-u), kc(K+6-u)), u = 0..37 (clamped outside [1,255]).
    // Loaded AFTER phase 1 so the two coefficient sets are never both live.
    {
      const int K = 256 - 32 * s;
      half2_t P[38];
#pragma unroll
      for (int u = 0; u < 38; ++u) {
        const int kx = K + 7 - u;
        const int ky = kx - 1;
        const float px = (kx >= 1 && kx <= 255) ? (float)kx * crow[kx] : 0.0f;
        const float py = (ky >= 1 && ky <= 255) ? (float)ky * crow[ky] : 0.0f;
        P[u] = __builtin_bit_cast(half2_t, __builtin_amdgcn_cvt_pkrtz(px, py));
      }

      // Prime window chunks for it=16; rolling offsets for the it=17 fetch.
      // Chunk cix byte offset at iter it: (64s + 16cix + 16it) & 508.
      uint4 cw0 = *(const uint4*)(Hb + ((64 * s + 0  + 256) & 508));
      uint4 cw1 = *(const uint4*)(Hb + ((64 * s + 16 + 256) & 508));
      uint4 cw2 = *(const uint4*)(Hb + ((64 * s + 32 + 256) & 508));
      uint4 cw3 = *(const uint4*)(Hb + ((64 * s + 48 + 256) & 508));
      int ro0 = (64 * s + 0  + 272) & 508;
      int ro1 = (64 * s + 16 + 272) & 508;
      int ro2 = (64 * s + 32 + 272) & 508;
      int ro3 = (64 * s + 48 + 272) & 508;

#pragma unroll 2
      for (int it = 16; it < 64; ++it) {
        // Prefetch window chunks for it+1 (ordering vs this iter's ds_write
        // is safe: lane7-chunk3 is overridden by qn next iter).
        const uint4 pw0 = *(const uint4*)(Hb + ro0);
        const uint4 pw1 = *(const uint4*)(Hb + ro1);
        const uint4 pw2 = *(const uint4*)(Hb + ro2);
        const uint4 pw3 = *(const uint4*)(Hb + ro3);
        ro0 = (ro0 + 16) & 508; ro1 = (ro1 + 16) & 508;
        ro2 = (ro2 + 16) & 508; ro3 = (ro3 + 16) & 508;

        // Lane-7 substitution: newest 8 h's come from registers.
        uint4 w3u;
        w3u.x = is7 ? qn.x : cw3.x;
        w3u.y = is7 ? qn.y : cw3.y;
        w3u.z = is7 ? qn.z : cw3.z;
        w3u.w = is7 ? qn.w : cw3.w;

        half2_t B0 = {0, 0}, B1 = {0, 0}, B2 = {0, 0}, B3 = {0, 0};
        half2_t B4 = {0, 0}, B5 = {0, 0}, B6 = {0, 0}, B7 = {0, 0};
        DOTQ(P, cw0.x, 0)  DOTQ(P, cw0.y, 2)
        DOTQ(P, cw0.z, 4)  DOTQ(P, cw0.w, 6)
        DOTQ(P, cw1.x, 8)  DOTQ(P, cw1.y, 10)
        DOTQ(P, cw1.z, 12) DOTQ(P, cw1.w, 14)
        DOTQ(P, cw2.x, 16) DOTQ(P, cw2.y, 18)
        DOTQ(P, cw2.z, 20) DOTQ(P, cw2.w, 22)
        DOTQ(P, w3u.x, 24) DOTQ(P, w3u.y, 26)
        DOTQ(P, w3u.z, 28) DOTQ(P, w3u.w, 30)

        ITER_TAIL(a0 * ivA.x)

        // Rotate prefetched window into place.
        cw0 = pw0; cw1 = pw1; cw2 = pw2; cw3 = pw3;
      }
    }
  }
}

extern "C" void kernel_launch(void* const* d_in, const int* in_sizes, int n_in,
                              void* d_out, int out_size, void* d_ws, size_t ws_size,
                              hipStream_t stream) {
  const float* c = (const float*)d_in[0];
  float* out = (float*)d_out;
  const int nrows = in_sizes[0] / CLEN;
  const int nblocks = (nrows + ROWS_PER_BLOCK - 1) / ROWS_PER_BLOCK;
  hipLaunchKernelGGL(cep2ir_kernel, dim3(nblocks), dim3(THREADS), 0, stream,
                     c, out, nrows);
}

// Round 13
// 401.823 us; speedup vs baseline: 1.0221x; 1.0221x over previous
//
#include <hip/hip_runtime.h>
#include <math.h>

// CepstrumToImpulseResponse: per row r (131072 rows):
//   h[0] = exp(c[0]);  h[n] = (1/n) * sum_{k=1}^{min(n,255)} (k*c_k) * h[n-k]
//
// R13 = R11 (fdot2 -- R12 proved pk_fma_f16 has no rate advantage; every FP
// MAC path on gfx950 = 1 MAC/lane-slot/cyc) + three instruction-count trims:
//  (t2) Phase-0: 64-wide window for it<8 (P0[14], own scope, loaded before
//       P1/P2 -> no coexistent coefficient sets). Saves 3.6% of dots; the
//       skipped terms are exact zeros -> bit-identical output.
//  (t3) ds_swizzle reduce: the 3 DPP-mov VALU ops per row8_sum become
//       ds_swizzle (xor1/2/4 butterfly, same tree -> bit-identical), moving
//       24 instrs/iter from the saturated VALU to the ~50%-idle LDS pipe.
//  (t4) Phase-2 ping-pong 2x unroll: kills the 16 v_mov window-rotation.
// Launch bounds pinned at (256,4): (256,8) spilled twice (R6/R9).
//
// Core structure: 8 rows/wave (8 lanes/row), J=8 outputs/iter, per-row
// 256-half f16 ring, v_dot2_f32_f16 vs packed f16x2 coeff pairs, 8-lane
// butterfly reduce, f32 serial fixup k=1..7, lane-7 register forwarding of
// the newest 8 h's, 1-iter window prefetch, register output staging,
// 256B/row coalesced flush every 8 iters.

constexpr int ROWS_PER_BLOCK = 32;   // 4 waves x 8 rows
constexpr int THREADS = 256;
constexpr int CLEN = 256;            // c row length (M+1)
constexpr int NOUT = 512;            // IR length
constexpr int RHALVES = 264;         // 256-half ring (512B) + 8 pad halves

typedef float f4 __attribute__((ext_vector_type(4)));
typedef _Float16 half2_t __attribute__((ext_vector_type(2)));

// Sum v across each aligned 8-lane group via ds_swizzle butterfly
// (xor 1, 2, 4); every lane gets the group total. BitMode offsets:
// (xor<<10)|(or<<5)|and(0x1F): 0x041F, 0x081F, 0x101F.
__device__ __forceinline__ float row8_sum(float v) {
  int x;
  x = __builtin_amdgcn_ds_swizzle(__float_as_int(v), 0x041F);
  v += __int_as_float(x);
  x = __builtin_amdgcn_ds_swizzle(__float_as_int(v), 0x081F);
  v += __int_as_float(x);
  x = __builtin_amdgcn_ds_swizzle(__float_as_int(v), 0x101F);
  v += __int_as_float(x);
  return v;
}

// One window pair (2 f16 in wu) against 8 outputs; output j uses P[ub+7-j].
#define DOTQ(P, wu, ub)                                                \
      { const half2_t q = __builtin_bit_cast(half2_t, (wu));           \
        A0 = __builtin_amdgcn_fdot2(q, P[(ub) + 7], A0, false);        \
        A1 = __builtin_amdgcn_fdot2(q, P[(ub) + 6], A1, false);        \
        A2 = __builtin_amdgcn_fdot2(q, P[(ub) + 5], A2, false);        \
        A3 = __builtin_amdgcn_fdot2(q, P[(ub) + 4], A3, false);        \
        A4 = __builtin_amdgcn_fdot2(q, P[(ub) + 3], A4, false);        \
        A5 = __builtin_amdgcn_fdot2(q, P[(ub) + 2], A5, false);        \
        A6 = __builtin_amdgcn_fdot2(q, P[(ub) + 1], A6, false);        \
        A7 = __builtin_amdgcn_fdot2(q, P[(ub) + 0], A7, false); }

// Reduce + fixup + ring write + staging/flush (shared by all phases).
#define ITER_TAIL(Y0EXPR)                                                \
      const float a0 = row8_sum(A0);                                     \
      const float a1 = row8_sum(A1);                                     \
      const float a2 = row8_sum(A2);                                     \
      const float a3 = row8_sum(A3);                                     \
      const float a4 = row8_sum(A4);                                     \
      const float a5 = row8_sum(A5);                                     \
      const float a6 = row8_sum(A6);                                     \
      const float a7 = row8_sum(A7);                                     \
      const int n = it * 8;                                              \
      const f4 ivA = *(const f4*)(&INV[n]);                              \
      const f4 ivB = *(const f4*)(&INV[n + 4]);                          \
      const float y0 = (Y0EXPR);                                         \
      const float y1 = fmaf(kc1, y0, a1) * ivA.y;                        \
      const float y2 = fmaf(kc1, y1, fmaf(kc2, y0, a2)) * ivA.z;         \
      const float y3 = fmaf(kc1, y2, fmaf(kc2, y1,                       \
                          fmaf(kc3, y0, a3))) * ivA.w;                   \
      const float y4 = fmaf(kc1, y3, fmaf(kc2, y2, fmaf(kc3, y1,         \
                          fmaf(kc4, y0, a4)))) * ivB.x;                  \
      const float y5 = fmaf(kc1, y4, fmaf(kc2, y3, fmaf(kc3, y2,         \
                          fmaf(kc4, y1, fmaf(kc5, y0, a5))))) * ivB.y;   \
      const float y6 = fmaf(kc1, y5, fmaf(kc2, y4, fmaf(kc3, y3,         \
                          fmaf(kc4, y2, fmaf(kc5, y1,                    \
                          fmaf(kc6, y0, a6)))))) * ivB.z;                \
      const float y7 = fmaf(kc1, y6, fmaf(kc2, y5, fmaf(kc3, y4,         \
                          fmaf(kc4, y3, fmaf(kc5, y2, fmaf(kc6, y1,      \
                          fmaf(kc7, y0, a7)))))))  * ivB.w;              \
      uint4 wq;                                                          \
      wq.x = __builtin_bit_cast(uint, __builtin_amdgcn_cvt_pkrtz(y0, y1)); \
      wq.y = __builtin_bit_cast(uint, __builtin_amdgcn_cvt_pkrtz(y2, y3)); \
      wq.z = __builtin_bit_cast(uint, __builtin_amdgcn_cvt_pkrtz(y4, y5)); \
      wq.w = __builtin_bit_cast(uint, __builtin_amdgcn_cvt_pkrtz(y6, y7)); \
      qn = wq;                                                           \
      wo = (wo + 16) & 508;                                              \
      if (s == 0) {                                                      \
        *(uint4*)(Hb + wo) = wq;   /* same-wave DS ops are in-order */   \
      }                                                                  \
      if ((it & 7) == s) {                                               \
        ys0 = y0; ys1 = y1; ys2 = y2; ys3 = y3;                          \
        ys4 = y4; ys5 = y5; ys6 = y6; ys7 = y7;                          \
      }                                                                  \
      if ((it & 7) == 7) {                                               \
        f4 v0; v0.x = ys0; v0.y = ys1; v0.z = ys2; v0.w = ys3;           \
        f4 v1; v1.x = ys4; v1.y = ys5; v1.z = ys6; v1.w = ys7;           \
        *(f4*)(gp) = v0;                                                 \
        *(f4*)(gp + 4) = v1;                                             \
        gp += 64;                                                        \
      }

// Phase-2 iteration body: window regs W0..W3 (current), N0..N3 (prefetch
// destination for it+1). Roles ping-pong across the 2x-unrolled loop.
#define P2_BODY(W0, W1, W2, W3, N0, N1, N2, N3)                          \
    {                                                                    \
      N0 = *(const uint4*)(Hb + ro0);                                    \
      N1 = *(const uint4*)(Hb + ro1);                                    \
      N2 = *(const uint4*)(Hb + ro2);                                    \
      N3 = *(const uint4*)(Hb + ro3);                                    \
      ro0 = (ro0 + 16) & 508; ro1 = (ro1 + 16) & 508;                    \
      ro2 = (ro2 + 16) & 508; ro3 = (ro3 + 16) & 508;                    \
      uint4 w3u;                                                         \
      w3u.x = is7 ? qn.x : W3.x;                                         \
      w3u.y = is7 ? qn.y : W3.y;                                         \
      w3u.z = is7 ? qn.z : W3.z;                                         \
      w3u.w = is7 ? qn.w : W3.w;                                         \
      float A0 = 0.f, A1 = 0.f, A2 = 0.f, A3 = 0.f;                      \
      float A4 = 0.f, A5 = 0.f, A6 = 0.f, A7 = 0.f;                      \
      DOTQ(P, W0.x, 0)   DOTQ(P, W0.y, 2)                                \
      DOTQ(P, W0.z, 4)   DOTQ(P, W0.w, 6)                                \
      DOTQ(P, W1.x, 8)   DOTQ(P, W1.y, 10)                               \
      DOTQ(P, W1.z, 12)  DOTQ(P, W1.w, 14)                               \
      DOTQ(P, W2.x, 16)  DOTQ(P, W2.y, 18)                               \
      DOTQ(P, W2.z, 20)  DOTQ(P, W2.w, 22)                               \
      DOTQ(P, w3u.x, 24) DOTQ(P, w3u.y, 26)                              \
      DOTQ(P, w3u.z, 28) DOTQ(P, w3u.w, 30)                              \
      ITER_TAIL(a0 * ivA.x)                                              \
    }

__global__ __launch_bounds__(THREADS, 4) void cep2ir_kernel(
    const float* __restrict__ c, float* __restrict__ out, int nrows) {
  __shared__ ushort HF[ROWS_PER_BLOCK][RHALVES];   // f16 h-history rings
  __shared__ float INV[NOUT];

  const int tid = threadIdx.x;
  const int lane = tid & 63;
  const int wid = tid >> 6;
  const int s = lane & 7;                  // sublane within 8-lane row group
  const int rl = (wid << 3) | (lane >> 3); // row within block, 0..31

  for (int i = tid; i < NOUT; i += THREADS)
    INV[i] = (i == 0) ? 0.0f : 1.0f / (float)i;
  // Zero all rings (as uints; RHALVES is even -> rows stay uint-aligned).
  uint* hz = (uint*)&HF[0][0];
  for (int i = tid; i < ROWS_PER_BLOCK * RHALVES / 2; i += THREADS)
    hz[i] = 0u;
  __syncthreads();  // uniform: all threads reach this before any divergence

  const long long row = (long long)blockIdx.x * ROWS_PER_BLOCK + rl;
  if (row < nrows) {
    const float* __restrict__ crow = c + row * (long long)CLEN;

    const float kc1 = crow[1];
    const float kc2 = 2.0f * crow[2];
    const float kc3 = 3.0f * crow[3];
    const float kc4 = 4.0f * crow[4];
    const float kc5 = 5.0f * crow[5];
    const float kc6 = 6.0f * crow[6];
    const float kc7 = 7.0f * crow[7];
    const float h0val = expf(crow[0]);
    const bool is7 = (s == 7);

    char* __restrict__ Hb = (char*)&HF[rl][0];
    int wo = (-16) & 508;                    // ring write offset (bytes)
    float* __restrict__ gp = out + row * (long long)NOUT + 8 * s;

    uint4 qn; qn.x = 0u; qn.y = 0u; qn.z = 0u; qn.w = 0u;  // forwarded h's

    // Register output staging: lane s keeps the y's of the iteration with
    // (it&7)==s, then writes its own 32B slice at flush (coalesced).
    float ys0 = 0.f, ys1 = 0.f, ys2 = 0.f, ys3 = 0.f;
    float ys4 = 0.f, ys5 = 0.f, ys6 = 0.f, ys7 = 0.f;

    // ------------- Phase 0: it = 0..7, 64-wide window -------------
    // Lane s owns pos p = 8s + e, e = 0..7 (p 0 = h[n-64], p 63 = h[n-1]).
    // Coef k = K0 + j - e, K0 = 64 - 8s; P0[u] = (kc(K0+7-u), kc(K0+6-u)),
    // u = 0..13; pair pp (e = 2pp,2pp+1) for output j uses P0[2pp+7-j].
    // k over all lanes in [1,71] -> no guards. Ring byte of p:
    // (16it + 384 + 16s + 2e) mod 512; newest 8 h's = lane 7's whole chunk.
    {
      const int K0 = 64 - 8 * s;
      half2_t P0[14];
#pragma unroll
      for (int u = 0; u < 14; ++u) {
        const int kx = K0 + 7 - u;          // in [2,71]; ky = kx-1 >= 1
        P0[u] = __builtin_bit_cast(half2_t, __builtin_amdgcn_cvt_pkrtz(
                    (float)kx * crow[kx], (float)(kx - 1) * crow[kx - 1]));
      }
#pragma unroll 2
      for (int it = 0; it < 8; ++it) {
        const int b = (16 * it + 384 + 16 * s) & 508;
        const uint4 r0 = *(const uint4*)(Hb + b);
        uint4 u0;
        u0.x = is7 ? qn.x : r0.x;
        u0.y = is7 ? qn.y : r0.y;
        u0.z = is7 ? qn.z : r0.z;
        u0.w = is7 ? qn.w : r0.w;

        float A0 = 0.f, A1 = 0.f, A2 = 0.f, A3 = 0.f;
        float A4 = 0.f, A5 = 0.f, A6 = 0.f, A7 = 0.f;
        DOTQ(P0, u0.x, 0) DOTQ(P0, u0.y, 2)
        DOTQ(P0, u0.z, 4) DOTQ(P0, u0.w, 6)

        ITER_TAIL((it == 0) ? h0val : a0 * ivA.x)
      }
    }

    // ------------- Phase 1: it = 8..15, 128-wide window -------------
    // Lane s owns pos p = 16s + eps, eps = 0..15. K1 = 128 - 16s;
    // P1[u] = (kc(K1+7-u), kc(K1+6-u)), u = 0..21; pair pp uses P1[2pp+7-j].
    // k over all lanes in [2,135] -> no guards. Ring byte of p:
    // (16it + 256 + 32s + 2eps) mod 512. Newest 8 = lane 7's upper chunk.
    {
      const int K1 = 128 - 16 * s;
      half2_t P1[22];
#pragma unroll
      for (int u = 0; u < 22; ++u) {
        const int kx = K1 + 7 - u;          // in [2,135]
        P1[u] = __builtin_bit_cast(half2_t, __builtin_amdgcn_cvt_pkrtz(
                    (float)kx * crow[kx], (float)(kx - 1) * crow[kx - 1]));
      }
#pragma unroll 2
      for (int it = 8; it < 16; ++it) {
        const int b0 = (16 * it + 256 + 32 * s) & 508;
        const int b1 = (b0 + 16) & 508;
        const uint4 u0 = *(const uint4*)(Hb + b0);   // eps 0..7
        const uint4 u1r = *(const uint4*)(Hb + b1);  // eps 8..15
        uint4 u1;
        u1.x = is7 ? qn.x : u1r.x;
        u1.y = is7 ? qn.y : u1r.y;
        u1.z = is7 ? qn.z : u1r.z;
        u1.w = is7 ? qn.w : u1r.w;

        float A0 = 0.f, A1 = 0.f, A2 = 0.f, A3 = 0.f;
        float A4 = 0.f, A5 = 0.f, A6 = 0.f, A7 = 0.f;
        DOTQ(P1, u0.x, 0)  DOTQ(P1, u0.y, 2)
        DOTQ(P1, u0.z, 4)  DOTQ(P1, u0.w, 6)
        DOTQ(P1, u1.x, 8)  DOTQ(P1, u1.y, 10)
        DOTQ(P1, u1.z, 12) DOTQ(P1, u1.w, 14)

        ITER_TAIL(a0 * ivA.x)
      }
    }

    // ------------- Phase 2: it = 16..63, 256-wide window -------------
    // Lane s owns pos = 32s + eps, eps = 0..31. K = 256 - 32s.
    // P[u] = (kc(K+7-u), kc(K+6-u)), u = 0..37 (clamped outside [1,255]).
    // 2x-unrolled with ping-pong window registers (no rotation moves).
    {
      const int K = 256 - 32 * s;
      half2_t P[38];
#pragma unroll
      for (int u = 0; u < 38; ++u) {
        const int kx = K + 7 - u;
        const int ky = kx - 1;
        const float px = (kx >= 1 && kx <= 255) ? (float)kx * crow[kx] : 0.0f;
        const float py = (ky >= 1 && ky <= 255) ? (float)ky * crow[ky] : 0.0f;
        P[u] = __builtin_bit_cast(half2_t, __builtin_amdgcn_cvt_pkrtz(px, py));
      }

      // Prime window chunks for it=16; rolling offsets point at it=17.
      // Chunk cix byte offset at iter it: (64s + 16cix + 16it) & 508.
      uint4 cw0 = *(const uint4*)(Hb + ((64 * s + 0  + 256) & 508));
      uint4 cw1 = *(const uint4*)(Hb + ((64 * s + 16 + 256) & 508));
      uint4 cw2 = *(const uint4*)(Hb + ((64 * s + 32 + 256) & 508));
      uint4 cw3 = *(const uint4*)(Hb + ((64 * s + 48 + 256) & 508));
      int ro0 = (64 * s + 0  + 272) & 508;
      int ro1 = (64 * s + 16 + 272) & 508;
      int ro2 = (64 * s + 32 + 272) & 508;
      int ro3 = (64 * s + 48 + 272) & 508;
      uint4 pw0, pw1, pw2, pw3;

      for (int itp = 16; itp < 64; itp += 2) {
        { const int it = itp;
          P2_BODY(cw0, cw1, cw2, cw3, pw0, pw1, pw2, pw3) }
        { const int it = itp + 1;
          P2_BODY(pw0, pw1, pw2, pw3, cw0, cw1, cw2, cw3) }
      }
    }
  }
}

extern "C" void kernel_launch(void* const* d_in, const int* in_sizes, int n_in,
                              void* d_out, int out_size, void* d_ws, size_t ws_size,
                              hipStream_t stream) {
  const float* c = (const float*)d_in[0];
  float* out = (float*)d_out;
  const int nrows = in_sizes[0] / CLEN;
  const int nblocks = (nrows + ROWS_PER_BLOCK - 1) / ROWS_PER_BLOCK;
  hipLaunchKernelGGL(cep2ir_kernel, dim3(nblocks), dim3(THREADS), 0, stream,
                     c, out, nrows);
}

// Round 14
// 380.016 us; speedup vs baseline: 1.0807x; 1.0574x over previous
//
#include <hip/hip_runtime.h>
#include <math.h>

// CepstrumToImpulseResponse: per row r (131072 rows):
//   h[0] = exp(c[0]);  h[n] = (1/n) * sum_{k=1}^{min(n,255)} (k*c_k) * h[n-k]
//
// R14 = R13 with the reduce reverted to DPP (t3 regression isolated: the
// ds_swizzle butterfly put 3 serial LDS round-trips on the loop-carried
// path -- VALUBusy fell 98->91 but dur rose 376->402. DPP movs are 3
// back-to-back VALU ops, no lgkmcnt). Kept from R13:
//  (t2) Phase-0: 64-wide window for it<8 (3.8% fewer dots, exact zeros).
//  (t4) Phase-2 ping-pong 2x unroll (no window-rotation movs).
// MAC engine: v_dot2_f32_f16 (R12 proved all FP MAC paths on gfx950 issue
// 1 MAC/lane-slot/cyc; fdot2 has the cheapest tail). Launch bounds (256,4):
// (256,8) spilled twice (R6/R9).
//
// Core structure: 8 rows/wave (8 lanes/row), J=8 outputs/iter, per-row
// 256-half f16 ring, three-phase window (64/128/256-wide), DPP 8-lane
// butterfly reduce, f32 serial fixup k=1..7, lane-7 register forwarding of
// the newest 8 h's, 1-iter window prefetch, register output staging,
// 256B/row coalesced flush every 8 iters.

constexpr int ROWS_PER_BLOCK = 32;   // 4 waves x 8 rows
constexpr int THREADS = 256;
constexpr int CLEN = 256;            // c row length (M+1)
constexpr int NOUT = 512;            // IR length
constexpr int RHALVES = 264;         // 256-half ring (512B) + 8 pad halves

typedef float f4 __attribute__((ext_vector_type(4)));
typedef _Float16 half2_t __attribute__((ext_vector_type(2)));

// Sum v across each aligned 8-lane group; every lane gets the group total.
// quad_perm(1,0,3,2)=0xB1, quad_perm(2,3,0,1)=0x4E, row_half_mirror=0x141
__device__ __forceinline__ float row8_sum(float v) {
  int x;
  x = __builtin_amdgcn_update_dpp(0, __float_as_int(v), 0xB1, 0xF, 0xF, true);
  v += __int_as_float(x);
  x = __builtin_amdgcn_update_dpp(0, __float_as_int(v), 0x4E, 0xF, 0xF, true);
  v += __int_as_float(x);
  x = __builtin_amdgcn_update_dpp(0, __float_as_int(v), 0x141, 0xF, 0xF, true);
  v += __int_as_float(x);
  return v;
}

// One window pair (2 f16 in wu) against 8 outputs; output j uses P[ub+7-j].
#define DOTQ(P, wu, ub)                                                \
      { const half2_t q = __builtin_bit_cast(half2_t, (wu));           \
        A0 = __builtin_amdgcn_fdot2(q, P[(ub) + 7], A0, false);        \
        A1 = __builtin_amdgcn_fdot2(q, P[(ub) + 6], A1, false);        \
        A2 = __builtin_amdgcn_fdot2(q, P[(ub) + 5], A2, false);        \
        A3 = __builtin_amdgcn_fdot2(q, P[(ub) + 4], A3, false);        \
        A4 = __builtin_amdgcn_fdot2(q, P[(ub) + 3], A4, false);        \
        A5 = __builtin_amdgcn_fdot2(q, P[(ub) + 2], A5, false);        \
        A6 = __builtin_amdgcn_fdot2(q, P[(ub) + 1], A6, false);        \
        A7 = __builtin_amdgcn_fdot2(q, P[(ub) + 0], A7, false); }

// Reduce + fixup + ring write + staging/flush (shared by all phases).
#define ITER_TAIL(Y0EXPR)                                                \
      const float a0 = row8_sum(A0);                                     \
      const float a1 = row8_sum(A1);                                     \
      const float a2 = row8_sum(A2);                                     \
      const float a3 = row8_sum(A3);                                     \
      const float a4 = row8_sum(A4);                                     \
      const float a5 = row8_sum(A5);                                     \
      const float a6 = row8_sum(A6);                                     \
      const float a7 = row8_sum(A7);                                     \
      const int n = it * 8;                                              \
      const f4 ivA = *(const f4*)(&INV[n]);                              \
      const f4 ivB = *(const f4*)(&INV[n + 4]);                          \
      const float y0 = (Y0EXPR);                                         \
      const float y1 = fmaf(kc1, y0, a1) * ivA.y;                        \
      const float y2 = fmaf(kc1, y1, fmaf(kc2, y0, a2)) * ivA.z;         \
      const float y3 = fmaf(kc1, y2, fmaf(kc2, y1,                       \
                          fmaf(kc3, y0, a3))) * ivA.w;                   \
      const float y4 = fmaf(kc1, y3, fmaf(kc2, y2, fmaf(kc3, y1,         \
                          fmaf(kc4, y0, a4)))) * ivB.x;                  \
      const float y5 = fmaf(kc1, y4, fmaf(kc2, y3, fmaf(kc3, y2,         \
                          fmaf(kc4, y1, fmaf(kc5, y0, a5))))) * ivB.y;   \
      const float y6 = fmaf(kc1, y5, fmaf(kc2, y4, fmaf(kc3, y3,         \
                          fmaf(kc4, y2, fmaf(kc5, y1,                    \
                          fmaf(kc6, y0, a6)))))) * ivB.z;                \
      const float y7 = fmaf(kc1, y6, fmaf(kc2, y5, fmaf(kc3, y4,         \
                          fmaf(kc4, y3, fmaf(kc5, y2, fmaf(kc6, y1,      \
                          fmaf(kc7, y0, a7)))))))  * ivB.w;              \
      uint4 wq;                                                          \
      wq.x = __builtin_bit_cast(uint, __builtin_amdgcn_cvt_pkrtz(y0, y1)); \
      wq.y = __builtin_bit_cast(uint, __builtin_amdgcn_cvt_pkrtz(y2, y3)); \
      wq.z = __builtin_bit_cast(uint, __builtin_amdgcn_cvt_pkrtz(y4, y5)); \
      wq.w = __builtin_bit_cast(uint, __builtin_amdgcn_cvt_pkrtz(y6, y7)); \
      qn = wq;                                                           \
      wo = (wo + 16) & 508;                                              \
      if (s == 0) {                                                      \
        *(uint4*)(Hb + wo) = wq;   /* same-wave DS ops are in-order */   \
      }                                                                  \
      if ((it & 7) == s) {                                               \
        ys0 = y0; ys1 = y1; ys2 = y2; ys3 = y3;                          \
        ys4 = y4; ys5 = y5; ys6 = y6; ys7 = y7;                          \
      }                                                                  \
      if ((it & 7) == 7) {                                               \
        f4 v0; v0.x = ys0; v0.y = ys1; v0.z = ys2; v0.w = ys3;           \
        f4 v1; v1.x = ys4; v1.y = ys5; v1.z = ys6; v1.w = ys7;           \
        *(f4*)(gp) = v0;                                                 \
        *(f4*)(gp + 4) = v1;                                             \
        gp += 64;                                                        \
      }

// Phase-2 iteration body: window regs W0..W3 (current), N0..N3 (prefetch
// destination for it+1). Roles ping-pong across the 2x-unrolled loop.
#define P2_BODY(W0, W1, W2, W3, N0, N1, N2, N3)                          \
    {                                                                    \
      N0 = *(const uint4*)(Hb + ro0);                                    \
      N1 = *(const uint4*)(Hb + ro1);                                    \
      N2 = *(const uint4*)(Hb + ro2);                                    \
      N3 = *(const uint4*)(Hb + ro3);                                    \
      ro0 = (ro0 + 16) & 508; ro1 = (ro1 + 16) & 508;                    \
      ro2 = (ro2 + 16) & 508; ro3 = (ro3 + 16) & 508;                    \
      uint4 w3u;                                                         \
      w3u.x = is7 ? qn.x : W3.x;                                         \
      w3u.y = is7 ? qn.y : W3.y;                                         \
      w3u.z = is7 ? qn.z : W3.z;                                         \
      w3u.w = is7 ? qn.w : W3.w;                                         \
      float A0 = 0.f, A1 = 0.f, A2 = 0.f, A3 = 0.f;                      \
      float A4 = 0.f, A5 = 0.f, A6 = 0.f, A7 = 0.f;                      \
      DOTQ(P, W0.x, 0)   DOTQ(P, W0.y, 2)                                \
      DOTQ(P, W0.z, 4)   DOTQ(P, W0.w, 6)                                \
      DOTQ(P, W1.x, 8)   DOTQ(P, W1.y, 10)                               \
      DOTQ(P, W1.z, 12)  DOTQ(P, W1.w, 14)                               \
      DOTQ(P, W2.x, 16)  DOTQ(P, W2.y, 18)                               \
      DOTQ(P, W2.z, 20)  DOTQ(P, W2.w, 22)                               \
      DOTQ(P, w3u.x, 24) DOTQ(P, w3u.y, 26)                              \
      DOTQ(P, w3u.z, 28) DOTQ(P, w3u.w, 30)                              \
      ITER_TAIL(a0 * ivA.x)                                              \
    }

__global__ __launch_bounds__(THREADS, 4) void cep2ir_kernel(
    const float* __restrict__ c, float* __restrict__ out, int nrows) {
  __shared__ ushort HF[ROWS_PER_BLOCK][RHALVES];   // f16 h-history rings
  __shared__ float INV[NOUT];

  const int tid = threadIdx.x;
  const int lane = tid & 63;
  const int wid = tid >> 6;
  const int s = lane & 7;                  // sublane within 8-lane row group
  const int rl = (wid << 3) | (lane >> 3); // row within block, 0..31

  for (int i = tid; i < NOUT; i += THREADS)
    INV[i] = (i == 0) ? 0.0f : 1.0f / (float)i;
  // Zero all rings (as uints; RHALVES is even -> rows stay uint-aligned).
  uint* hz = (uint*)&HF[0][0];
  for (int i = tid; i < ROWS_PER_BLOCK * RHALVES / 2; i += THREADS)
    hz[i] = 0u;
  __syncthreads();  // uniform: all threads reach this before any divergence

  const long long row = (long long)blockIdx.x * ROWS_PER_BLOCK + rl;
  if (row < nrows) {
    const float* __restrict__ crow = c + row * (long long)CLEN;

    const float kc1 = crow[1];
    const float kc2 = 2.0f * crow[2];
    const float kc3 = 3.0f * crow[3];
    const float kc4 = 4.0f * crow[4];
    const float kc5 = 5.0f * crow[5];
    const float kc6 = 6.0f * crow[6];
    const float kc7 = 7.0f * crow[7];
    const float h0val = expf(crow[0]);
    const bool is7 = (s == 7);

    char* __restrict__ Hb = (char*)&HF[rl][0];
    int wo = (-16) & 508;                    // ring write offset (bytes)
    float* __restrict__ gp = out + row * (long long)NOUT + 8 * s;

    uint4 qn; qn.x = 0u; qn.y = 0u; qn.z = 0u; qn.w = 0u;  // forwarded h's

    // Register output staging: lane s keeps the y's of the iteration with
    // (it&7)==s, then writes its own 32B slice at flush (coalesced).
    float ys0 = 0.f, ys1 = 0.f, ys2 = 0.f, ys3 = 0.f;
    float ys4 = 0.f, ys5 = 0.f, ys6 = 0.f, ys7 = 0.f;

    // ------------- Phase 0: it = 0..7, 64-wide window -------------
    // Lane s owns pos p = 8s + e, e = 0..7 (p 0 = h[n-64], p 63 = h[n-1]).
    // Coef k = K0 + j - e, K0 = 64 - 8s; P0[u] = (kc(K0+7-u), kc(K0+6-u)),
    // u = 0..13; pair pp (e = 2pp,2pp+1) for output j uses P0[2pp+7-j].
    // k over all lanes in [2,71] -> no guards. Ring byte of p:
    // (16it + 384 + 16s + 2e) mod 512; newest 8 h's = lane 7's whole chunk.
    {
      const int K0 = 64 - 8 * s;
      half2_t P0[14];
#pragma unroll
      for (int u = 0; u < 14; ++u) {
        const int kx = K0 + 7 - u;          // in [2,71]; ky = kx-1 >= 1
        P0[u] = __builtin_bit_cast(half2_t, __builtin_amdgcn_cvt_pkrtz(
                    (float)kx * crow[kx], (float)(kx - 1) * crow[kx - 1]));
      }
#pragma unroll 2
      for (int it = 0; it < 8; ++it) {
        const int b = (16 * it + 384 + 16 * s) & 508;
        const uint4 r0 = *(const uint4*)(Hb + b);
        uint4 u0;
        u0.x = is7 ? qn.x : r0.x;
        u0.y = is7 ? qn.y : r0.y;
        u0.z = is7 ? qn.z : r0.z;
        u0.w = is7 ? qn.w : r0.w;

        float A0 = 0.f, A1 = 0.f, A2 = 0.f, A3 = 0.f;
        float A4 = 0.f, A5 = 0.f, A6 = 0.f, A7 = 0.f;
        DOTQ(P0, u0.x, 0) DOTQ(P0, u0.y, 2)
        DOTQ(P0, u0.z, 4) DOTQ(P0, u0.w, 6)

        ITER_TAIL((it == 0) ? h0val : a0 * ivA.x)
      }
    }

    // ------------- Phase 1: it = 8..15, 128-wide window -------------
    // Lane s owns pos p = 16s + eps, eps = 0..15. K1 = 128 - 16s;
    // P1[u] = (kc(K1+7-u), kc(K1+6-u)), u = 0..21; pair pp uses P1[2pp+7-j].
    // k over all lanes in [2,135] -> no guards. Ring byte of p:
    // (16it + 256 + 32s + 2eps) mod 512. Newest 8 = lane 7's upper chunk.
    {
      const int K1 = 128 - 16 * s;
      half2_t P1[22];
#pragma unroll
      for (int u = 0; u < 22; ++u) {
        const int kx = K1 + 7 - u;          // in [2,135]
        P1[u] = __builtin_bit_cast(half2_t, __builtin_amdgcn_cvt_pkrtz(
                    (float)kx * crow[kx], (float)(kx - 1) * crow[kx - 1]));
      }
#pragma unroll 2
      for (int it = 8; it < 16; ++it) {
        const int b0 = (16 * it + 256 + 32 * s) & 508;
        const int b1 = (b0 + 16) & 508;
        const uint4 u0 = *(const uint4*)(Hb + b0);   // eps 0..7
        const uint4 u1r = *(const uint4*)(Hb + b1);  // eps 8..15
        uint4 u1;
        u1.x = is7 ? qn.x : u1r.x;
        u1.y = is7 ? qn.y : u1r.y;
        u1.z = is7 ? qn.z : u1r.z;
        u1.w = is7 ? qn.w : u1r.w;

        float A0 = 0.f, A1 = 0.f, A2 = 0.f, A3 = 0.f;
        float A4 = 0.f, A5 = 0.f, A6 = 0.f, A7 = 0.f;
        DOTQ(P1, u0.x, 0)  DOTQ(P1, u0.y, 2)
        DOTQ(P1, u0.z, 4)  DOTQ(P1, u0.w, 6)
        DOTQ(P1, u1.x, 8)  DOTQ(P1, u1.y, 10)
        DOTQ(P1, u1.z, 12) DOTQ(P1, u1.w, 14)

        ITER_TAIL(a0 * ivA.x)
      }
    }

    // ------------- Phase 2: it = 16..63, 256-wide window -------------
    // Lane s owns pos = 32s + eps, eps = 0..31. K = 256 - 32s.
    // P[u] = (kc(K+7-u), kc(K+6-u)), u = 0..37 (clamped outside [1,255]).
    // 2x-unrolled with ping-pong window registers (no rotation moves).
    {
      const int K = 256 - 32 * s;
      half2_t P[38];
#pragma unroll
      for (int u = 0; u < 38; ++u) {
        const int kx = K + 7 - u;
        const int ky = kx - 1;
        const float px = (kx >= 1 && kx <= 255) ? (float)kx * crow[kx] : 0.0f;
        const float py = (ky >= 1 && ky <= 255) ? (float)ky * crow[ky] : 0.0f;
        P[u] = __builtin_bit_cast(half2_t, __builtin_amdgcn_cvt_pkrtz(px, py));
      }

      // Prime window chunks for it=16; rolling offsets point at it=17.
      // Chunk cix byte offset at iter it: (64s + 16cix + 16it) & 508.
      uint4 cw0 = *(const uint4*)(Hb + ((64 * s + 0  + 256) & 508));
      uint4 cw1 = *(const uint4*)(Hb + ((64 * s + 16 + 256) & 508));
      uint4 cw2 = *(const uint4*)(Hb + ((64 * s + 32 + 256) & 508));
      uint4 cw3 = *(const uint4*)(Hb + ((64 * s + 48 + 256) & 508));
      int ro0 = (64 * s + 0  + 272) & 508;
      int ro1 = (64 * s + 16 + 272) & 508;
      int ro2 = (64 * s + 32 + 272) & 508;
      int ro3 = (64 * s + 48 + 272) & 508;
      uint4 pw0, pw1, pw2, pw3;

      for (int itp = 16; itp < 64; itp += 2) {
        { const int it = itp;
          P2_BODY(cw0, cw1, cw2, cw3, pw0, pw1, pw2, pw3) }
        { const int it = itp + 1;
          P2_BODY(pw0, pw1, pw2, pw3, cw0, cw1, cw2, cw3) }
      }
    }
  }
}

extern "C" void kernel_launch(void* const* d_in, const int* in_sizes, int n_in,
                              void* d_out, int out_size, void* d_ws, size_t ws_size,
                              hipStream_t stream) {
  const float* c = (const float*)d_in[0];
  float* out = (float*)d_out;
  const int nrows = in_sizes[0] / CLEN;
  const int nblocks = (nrows + ROWS_PER_BLOCK - 1) / ROWS_PER_BLOCK;
  hipLaunchKernelGGL(cep2ir_kernel, dim3(nblocks), dim3(THREADS), 0, stream,
                     c, out, nrows);
}

// Round 15
// 375.698 us; speedup vs baseline: 1.0932x; 1.0115x over previous
//
#include <hip/hip_runtime.h>
#include <math.h>

// CepstrumToImpulseResponse: per row r (131072 rows):
//   h[0] = exp(c[0]);  h[n] = (1/n) * sum_{k=1}^{min(n,255)} (k*c_k) * h[n-k]
//
// R15 = R14 with the 8-lane butterfly reduce written as explicit DPP-fused
// adds (inline asm v_add_f32 + quad_perm/row_half_mirror modifiers = 1 instr
// per stage) instead of update_dpp(mov) + add (2 instrs per stage unless
// LLVM's DPP-combine folds it). Bit-identical arithmetic; single-variable
// probe of whether the compiler was already fusing.
// Cycle model (reconciled w/ R14 counters): 837 issue-cyc/wave-iter ~=
// 128 fdot2 x 4cyc (VOP3P dot2 = half-issue-rate on SIMD-32; 1 MAC/lane/cyc
// proven across pk_f32/fdot2/pk_fma_f16) + ~100 tail instrs x 2cyc. Dots are
// 72% of issue at max HW MAC rate; reduce is the largest tail item.
//
// Carried: three-phase window (64/128/256 for it<8/<16/>=16; exact-zero
// skips), per-row 256-half f16 ring, lane-7 register forwarding, 1-iter
// window prefetch + phase-2 ping-pong 2x unroll, f32 serial fixup k=1..7,
// register output staging, 256B/row coalesced flush. Launch bounds (256,4)
// pinned: (256,8) spilled twice (R6/R9).

constexpr int ROWS_PER_BLOCK = 32;   // 4 waves x 8 rows
constexpr int THREADS = 256;
constexpr int CLEN = 256;            // c row length (M+1)
constexpr int NOUT = 512;            // IR length
constexpr int RHALVES = 264;         // 256-half ring (512B) + 8 pad halves

typedef float f4 __attribute__((ext_vector_type(4)));
typedef _Float16 half2_t __attribute__((ext_vector_type(2)));

// Sum v across each aligned 8-lane group; every lane gets the group total.
// Three DPP-fused adds: xor1 (quad_perm [1,0,3,2]), xor2 (quad_perm
// [2,3,0,1]), xor4 (row_half_mirror). dst = DPP(src0) + src1, all same reg.
__device__ __forceinline__ float row8_sum(float v) {
  asm("v_add_f32 %0, %0, %0 quad_perm:[1,0,3,2] row_mask:0xf bank_mask:0xf"
      : "+v"(v));
  asm("v_add_f32 %0, %0, %0 quad_perm:[2,3,0,1] row_mask:0xf bank_mask:0xf"
      : "+v"(v));
  asm("v_add_f32 %0, %0, %0 row_half_mirror row_mask:0xf bank_mask:0xf"
      : "+v"(v));
  return v;
}

// One window pair (2 f16 in wu) against 8 outputs; output j uses P[ub+7-j].
#define DOTQ(P, wu, ub)                                                \
      { const half2_t q = __builtin_bit_cast(half2_t, (wu));           \
        A0 = __builtin_amdgcn_fdot2(q, P[(ub) + 7], A0, false);        \
        A1 = __builtin_amdgcn_fdot2(q, P[(ub) + 6], A1, false);        \
        A2 = __builtin_amdgcn_fdot2(q, P[(ub) + 5], A2, false);        \
        A3 = __builtin_amdgcn_fdot2(q, P[(ub) + 4], A3, false);        \
        A4 = __builtin_amdgcn_fdot2(q, P[(ub) + 3], A4, false);        \
        A5 = __builtin_amdgcn_fdot2(q, P[(ub) + 2], A5, false);        \
        A6 = __builtin_amdgcn_fdot2(q, P[(ub) + 1], A6, false);        \
        A7 = __builtin_amdgcn_fdot2(q, P[(ub) + 0], A7, false); }

// Reduce + fixup + ring write + staging/flush (shared by all phases).
#define ITER_TAIL(Y0EXPR)                                                \
      const float a0 = row8_sum(A0);                                     \
      const float a1 = row8_sum(A1);                                     \
      const float a2 = row8_sum(A2);                                     \
      const float a3 = row8_sum(A3);                                     \
      const float a4 = row8_sum(A4);                                     \
      const float a5 = row8_sum(A5);                                     \
      const float a6 = row8_sum(A6);                                     \
      const float a7 = row8_sum(A7);                                     \
      const int n = it * 8;                                              \
      const f4 ivA = *(const f4*)(&INV[n]);                              \
      const f4 ivB = *(const f4*)(&INV[n + 4]);                          \
      const float y0 = (Y0EXPR);                                         \
      const float y1 = fmaf(kc1, y0, a1) * ivA.y;                        \
      const float y2 = fmaf(kc1, y1, fmaf(kc2, y0, a2)) * ivA.z;         \
      const float y3 = fmaf(kc1, y2, fmaf(kc2, y1,                       \
                          fmaf(kc3, y0, a3))) * ivA.w;                   \
      const float y4 = fmaf(kc1, y3, fmaf(kc2, y2, fmaf(kc3, y1,         \
                          fmaf(kc4, y0, a4)))) * ivB.x;                  \
      const float y5 = fmaf(kc1, y4, fmaf(kc2, y3, fmaf(kc3, y2,         \
                          fmaf(kc4, y1, fmaf(kc5, y0, a5))))) * ivB.y;   \
      const float y6 = fmaf(kc1, y5, fmaf(kc2, y4, fmaf(kc3, y3,         \
                          fmaf(kc4, y2, fmaf(kc5, y1,                    \
                          fmaf(kc6, y0, a6)))))) * ivB.z;                \
      const float y7 = fmaf(kc1, y6, fmaf(kc2, y5, fmaf(kc3, y4,         \
                          fmaf(kc4, y3, fmaf(kc5, y2, fmaf(kc6, y1,      \
                          fmaf(kc7, y0, a7)))))))  * ivB.w;              \
      uint4 wq;                                                          \
      wq.x = __builtin_bit_cast(uint, __builtin_amdgcn_cvt_pkrtz(y0, y1)); \
      wq.y = __builtin_bit_cast(uint, __builtin_amdgcn_cvt_pkrtz(y2, y3)); \
      wq.z = __builtin_bit_cast(uint, __builtin_amdgcn_cvt_pkrtz(y4, y5)); \
      wq.w = __builtin_bit_cast(uint, __builtin_amdgcn_cvt_pkrtz(y6, y7)); \
      qn = wq;                                                           \
      wo = (wo + 16) & 508;                                              \
      if (s == 0) {                                                      \
        *(uint4*)(Hb + wo) = wq;   /* same-wave DS ops are in-order */   \
      }                                                                  \
      if ((it & 7) == s) {                                               \
        ys0 = y0; ys1 = y1; ys2 = y2; ys3 = y3;                          \
        ys4 = y4; ys5 = y5; ys6 = y6; ys7 = y7;                          \
      }                                                                  \
      if ((it & 7) == 7) {                                               \
        f4 v0; v0.x = ys0; v0.y = ys1; v0.z = ys2; v0.w = ys3;           \
        f4 v1; v1.x = ys4; v1.y = ys5; v1.z = ys6; v1.w = ys7;           \
        *(f4*)(gp) = v0;                                                 \
        *(f4*)(gp + 4) = v1;                                             \
        gp += 64;                                                        \
      }

// Phase-2 iteration body: window regs W0..W3 (current), N0..N3 (prefetch
// destination for it+1). Roles ping-pong across the 2x-unrolled loop.
#define P2_BODY(W0, W1, W2, W3, N0, N1, N2, N3)                          \
    {                                                                    \
      N0 = *(const uint4*)(Hb + ro0);                                    \
      N1 = *(const uint4*)(Hb + ro1);                                    \
      N2 = *(const uint4*)(Hb + ro2);                                    \
      N3 = *(const uint4*)(Hb + ro3);                                    \
      ro0 = (ro0 + 16) & 508; ro1 = (ro1 + 16) & 508;                    \
      ro2 = (ro2 + 16) & 508; ro3 = (ro3 + 16) & 508;                    \
      uint4 w3u;                                                         \
      w3u.x = is7 ? qn.x : W3.x;                                         \
      w3u.y = is7 ? qn.y : W3.y;                                         \
      w3u.z = is7 ? qn.z : W3.z;                                         \
      w3u.w = is7 ? qn.w : W3.w;                                         \
      float A0 = 0.f, A1 = 0.f, A2 = 0.f, A3 = 0.f;                      \
      float A4 = 0.f, A5 = 0.f, A6 = 0.f, A7 = 0.f;                      \
      DOTQ(P, W0.x, 0)   DOTQ(P, W0.y, 2)                                \
      DOTQ(P, W0.z, 4)   DOTQ(P, W0.w, 6)                                \
      DOTQ(P, W1.x, 8)   DOTQ(P, W1.y, 10)                               \
      DOTQ(P, W1.z, 12)  DOTQ(P, W1.w, 14)                               \
      DOTQ(P, W2.x, 16)  DOTQ(P, W2.y, 18)                               \
      DOTQ(P, W2.z, 20)  DOTQ(P, W2.w, 22)                               \
      DOTQ(P, w3u.x, 24) DOTQ(P, w3u.y, 26)                              \
      DOTQ(P, w3u.z, 28) DOTQ(P, w3u.w, 30)                              \
      ITER_TAIL(a0 * ivA.x)                                              \
    }

__global__ __launch_bounds__(THREADS, 4) void cep2ir_kernel(
    const float* __restrict__ c, float* __restrict__ out, int nrows) {
  __shared__ ushort HF[ROWS_PER_BLOCK][RHALVES];   // f16 h-history rings
  __shared__ float INV[NOUT];

  const int tid = threadIdx.x;
  const int lane = tid & 63;
  const int wid = tid >> 6;
  const int s = lane & 7;                  // sublane within 8-lane row group
  const int rl = (wid << 3) | (lane >> 3); // row within block, 0..31

  for (int i = tid; i < NOUT; i += THREADS)
    INV[i] = (i == 0) ? 0.0f : 1.0f / (float)i;
  // Zero all rings (as uints; RHALVES is even -> rows stay uint-aligned).
  uint* hz = (uint*)&HF[0][0];
  for (int i = tid; i < ROWS_PER_BLOCK * RHALVES / 2; i += THREADS)
    hz[i] = 0u;
  __syncthreads();  // uniform: all threads reach this before any divergence

  const long long row = (long long)blockIdx.x * ROWS_PER_BLOCK + rl;
  if (row < nrows) {
    const float* __restrict__ crow = c + row * (long long)CLEN;

    const float kc1 = crow[1];
    const float kc2 = 2.0f * crow[2];
    const float kc3 = 3.0f * crow[3];
    const float kc4 = 4.0f * crow[4];
    const float kc5 = 5.0f * crow[5];
    const float kc6 = 6.0f * crow[6];
    const float kc7 = 7.0f * crow[7];
    const float h0val = expf(crow[0]);
    const bool is7 = (s == 7);

    char* __restrict__ Hb = (char*)&HF[rl][0];
    int wo = (-16) & 508;                    // ring write offset (bytes)
    float* __restrict__ gp = out + row * (long long)NOUT + 8 * s;

    uint4 qn; qn.x = 0u; qn.y = 0u; qn.z = 0u; qn.w = 0u;  // forwarded h's

    // Register output staging: lane s keeps the y's of the iteration with
    // (it&7)==s, then writes its own 32B slice at flush (coalesced).
    float ys0 = 0.f, ys1 = 0.f, ys2 = 0.f, ys3 = 0.f;
    float ys4 = 0.f, ys5 = 0.f, ys6 = 0.f, ys7 = 0.f;

    // ------------- Phase 0: it = 0..7, 64-wide window -------------
    // Lane s owns pos p = 8s + e, e = 0..7 (p 0 = h[n-64], p 63 = h[n-1]).
    // Coef k = K0 + j - e, K0 = 64 - 8s; P0[u] = (kc(K0+7-u), kc(K0+6-u)),
    // u = 0..13; pair pp (e = 2pp,2pp+1) for output j uses P0[2pp+7-j].
    // k over all lanes in [2,71] -> no guards. Ring byte of p:
    // (16it + 384 + 16s + 2e) mod 512; newest 8 h's = lane 7's whole chunk.
    {
      const int K0 = 64 - 8 * s;
      half2_t P0[14];
#pragma unroll
      for (int u = 0; u < 14; ++u) {
        const int kx = K0 + 7 - u;          // in [2,71]; ky = kx-1 >= 1
        P0[u] = __builtin_bit_cast(half2_t, __builtin_amdgcn_cvt_pkrtz(
                    (float)kx * crow[kx], (float)(kx - 1) * crow[kx - 1]));
      }
#pragma unroll 2
      for (int it = 0; it < 8; ++it) {
        const int b = (16 * it + 384 + 16 * s) & 508;
        const uint4 r0 = *(const uint4*)(Hb + b);
        uint4 u0;
        u0.x = is7 ? qn.x : r0.x;
        u0.y = is7 ? qn.y : r0.y;
        u0.z = is7 ? qn.z : r0.z;
        u0.w = is7 ? qn.w : r0.w;

        float A0 = 0.f, A1 = 0.f, A2 = 0.f, A3 = 0.f;
        float A4 = 0.f, A5 = 0.f, A6 = 0.f, A7 = 0.f;
        DOTQ(P0, u0.x, 0) DOTQ(P0, u0.y, 2)
        DOTQ(P0, u0.z, 4) DOTQ(P0, u0.w, 6)

        ITER_TAIL((it == 0) ? h0val : a0 * ivA.x)
      }
    }

    // ------------- Phase 1: it = 8..15, 128-wide window -------------
    // Lane s owns pos p = 16s + eps, eps = 0..15. K1 = 128 - 16s;
    // P1[u] = (kc(K1+7-u), kc(K1+6-u)), u = 0..21; pair pp uses P1[2pp+7-j].
    // k over all lanes in [2,135] -> no guards. Ring byte of p:
    // (16it + 256 + 32s + 2eps) mod 512. Newest 8 = lane 7's upper chunk.
    {
      const int K1 = 128 - 16 * s;
      half2_t P1[22];
#pragma unroll
      for (int u = 0; u < 22; ++u) {
        const int kx = K1 + 7 - u;          // in [2,135]
        P1[u] = __builtin_bit_cast(half2_t, __builtin_amdgcn_cvt_pkrtz(
                    (float)kx * crow[kx], (float)(kx - 1) * crow[kx - 1]));
      }
#pragma unroll 2
      for (int it = 8; it < 16; ++it) {
        const int b0 = (16 * it + 256 + 32 * s) & 508;
        const int b1 = (b0 + 16) & 508;
        const uint4 u0 = *(const uint4*)(Hb + b0);   // eps 0..7
        const uint4 u1r = *(const uint4*)(Hb + b1);  // eps 8..15
        uint4 u1;
        u1.x = is7 ? qn.x : u1r.x;
        u1.y = is7 ? qn.y : u1r.y;
        u1.z = is7 ? qn.z : u1r.z;
        u1.w = is7 ? qn.w : u1r.w;

        float A0 = 0.f, A1 = 0.f, A2 = 0.f, A3 = 0.f;
        float A4 = 0.f, A5 = 0.f, A6 = 0.f, A7 = 0.f;
        DOTQ(P1, u0.x, 0)  DOTQ(P1, u0.y, 2)
        DOTQ(P1, u0.z, 4)  DOTQ(P1, u0.w, 6)
        DOTQ(P1, u1.x, 8)  DOTQ(P1, u1.y, 10)
        DOTQ(P1, u1.z, 12) DOTQ(P1, u1.w, 14)

        ITER_TAIL(a0 * ivA.x)
      }
    }

    // ------------- Phase 2: it = 16..63, 256-wide window -------------
    // Lane s owns pos = 32s + eps, eps = 0..31. K = 256 - 32s.
    // P[u] = (kc(K+7-u), kc(K+6-u)), u = 0..37 (clamped outside [1,255]).
    // 2x-unrolled with ping-pong window registers (no rotation moves).
    {
      const int K = 256 - 32 * s;
      half2_t P[38];
#pragma unroll
      for (int u = 0; u < 38; ++u) {
        const int kx = K + 7 - u;
        const int ky = kx - 1;
        const float px = (kx >= 1 && kx <= 255) ? (float)kx * crow[kx] : 0.0f;
        const float py = (ky >= 1 && ky <= 255) ? (float)ky * crow[ky] : 0.0f;
        P[u] = __builtin_bit_cast(half2_t, __builtin_amdgcn_cvt_pkrtz(px, py));
      }

      // Prime window chunks for it=16; rolling offsets point at it=17.
      // Chunk cix byte offset at iter it: (64s + 16cix + 16it) & 508.
      uint4 cw0 = *(const uint4*)(Hb + ((64 * s + 0  + 256) & 508));
      uint4 cw1 = *(const uint4*)(Hb + ((64 * s + 16 + 256) & 508));
      uint4 cw2 = *(const uint4*)(Hb + ((64 * s + 32 + 256) & 508));
      uint4 cw3 = *(const uint4*)(Hb + ((64 * s + 48 + 256) & 508));
      int ro0 = (64 * s + 0  + 272) & 508;
      int ro1 = (64 * s + 16 + 272) & 508;
      int ro2 = (64 * s + 32 + 272) & 508;
      int ro3 = (64 * s + 48 + 272) & 508;
      uint4 pw0, pw1, pw2, pw3;

      for (int itp = 16; itp < 64; itp += 2) {
        { const int it = itp;
          P2_BODY(cw0, cw1, cw2, cw3, pw0, pw1, pw2, pw3) }
        { const int it = itp + 1;
          P2_BODY(pw0, pw1, pw2, pw3, cw0, cw1, cw2, cw3) }
      }
    }
  }
}

extern "C" void kernel_launch(void* const* d_in, const int* in_sizes, int n_in,
                              void* d_out, int out_size, void* d_ws, size_t ws_size,
                              hipStream_t stream) {
  const float* c = (const float*)d_in[0];
  float* out = (float*)d_out;
  const int nrows = in_sizes[0] / CLEN;
  const int nblocks = (nrows + ROWS_PER_BLOCK - 1) / ROWS_PER_BLOCK;
  hipLaunchKernelGGL(cep2ir_kernel, dim3(nblocks), dim3(THREADS), 0, stream,
                     c, out, nrows);
}